// Round 1
// baseline (539.562 us; speedup 1.0000x reference)
//
#include <hip/hip_runtime.h>

#define E_N     100000
#define USER_N  100000
#define NB_ACC  512

__device__ __forceinline__ float leaky(float x) { return x > 0.f ? x : 0.5f * x; }

// -------- zero d_out --------
__global__ void zeroKernel(float4* __restrict__ p, int n4) {
  int i = blockIdx.x * blockDim.x + threadIdx.x;
  const int stride = gridDim.x * blockDim.x;
  const float4 z = make_float4(0.f, 0.f, 0.f, 0.f);
  for (; i < n4; i += stride) p[i] = z;
}

// -------- Stage A: edge[e,k] = (sum_d uE[src[e],d] * T[val[e],d,k]) * iE[tgt[e],k] --------
// wave handles 4 edges; lane = (j=edge-in-group, kq=k quad)
__global__ void stageAKernel(const float* __restrict__ uE, const float* __restrict__ iE,
                             const float* __restrict__ T,
                             const int* __restrict__ src, const int* __restrict__ tgt,
                             const int* __restrict__ val,
                             float* __restrict__ edge) {
  __shared__ float sSrc[4 * 4 * 68];
  const int tid  = threadIdx.x;
  const int lane = tid & 63;
  const int wave = __builtin_amdgcn_readfirstlane(tid >> 6);
  const int j    = lane >> 4;
  const int l16  = lane & 15;
  float* sS = sSrc + wave * (4 * 68);
  const int nGroups = E_N / 4;
  const int gw0 = blockIdx.x * 4 + wave;
  const int nW  = gridDim.x * 4;
  for (int g = gw0; g < nGroups; g += nW) {
    const int e0 = g * 4;
    const int srcj = src[e0 + j];
    #pragma unroll
    for (int it = 0; it < 4; ++it) {
      const int d = l16 + 16 * it;
      sS[j * 68 + d] = uE[(size_t)srcj * 64 + d];
    }
    const int vj = val[e0 + j];
    const int tj = tgt[e0 + j];
    const float4* Tp = (const float4*)(T + (size_t)vj * 4096) + l16;
    float4 acc = make_float4(0.f, 0.f, 0.f, 0.f);
    #pragma unroll 8
    for (int d = 0; d < 64; ++d) {
      const float4 t4 = Tp[d * 16];
      const float  sv = sS[j * 68 + d];
      acc.x += sv * t4.x; acc.y += sv * t4.y;
      acc.z += sv * t4.z; acc.w += sv * t4.w;
    }
    const float4 iv = *(const float4*)(iE + (size_t)tj * 64 + l16 * 4);
    float4 r;
    r.x = acc.x * iv.x; r.y = acc.y * iv.y;
    r.z = acc.z * iv.z; r.w = acc.w * iv.w;
    *(float4*)(edge + (size_t)(e0 + j) * 64 + l16 * 4) = r;
  }
}

// -------- einsum1: partial[d,h] += edge[e,d] * hyper[e,h]  (per-block partials) --------
// lane = d; wave w covers h in [w*32, w*32+32); hyper row via uniform (scalar) loads.
__global__ void hyperAccumKernel(const float* __restrict__ edge, const float* __restrict__ hyper,
                                 float* __restrict__ partials) {
  const int tid  = threadIdx.x;
  const int lane = tid & 63;
  const int h0   = __builtin_amdgcn_readfirstlane((tid >> 6) * 32);
  float acc[32];
  #pragma unroll
  for (int i = 0; i < 32; ++i) acc[i] = 0.f;
  for (int e = blockIdx.x; e < E_N; e += NB_ACC) {
    const float ev = edge[(size_t)e * 64 + lane];
    const float* hp = hyper + (size_t)e * 128 + h0;
    #pragma unroll
    for (int i = 0; i < 32; ++i) acc[i] += hp[i] * ev;
  }
  // store transposed layout: partial[b][h*64 + d]
  float* pp = partials + (size_t)blockIdx.x * 8192;
  #pragma unroll
  for (int i = 0; i < 32; ++i) pp[(h0 + i) * 64 + lane] = acc[i];
}

// -------- reduce partials over blocks + leaky -> HEt[h*64+d] = act(HE[d][h]) --------
__global__ void reduceHEKernel(const float* __restrict__ partials, float* __restrict__ HEt) {
  const int i = blockIdx.x * 256 + threadIdx.x;   // 0..8191
  float s = 0.f;
  for (int b = 0; b < NB_ACC; ++b) s += partials[(size_t)b * 8192 + i];
  HEt[i] = leaky(s);
}

// -------- einsum2 + residual (in place): edge[e,d] = act(sum_h hyper[e,h]*HEt[h,d]) + edge[e,d]
// tile of 64 edges per block; lane = e_local; wave w covers d in [w*16, w*16+16);
// HEt via uniform scalar loads, hyper tile staged in LDS (pad 132).
__global__ void nodeUpdateKernel(const float* __restrict__ HEt, const float* __restrict__ hyper,
                                 float* __restrict__ edge) {
  __shared__ float sHy[64 * 132];
  const int tid   = threadIdx.x;
  const int lane  = tid & 63;
  const int waveS = __builtin_amdgcn_readfirstlane(tid >> 6);
  const int nT = (E_N + 63) >> 6;
  for (int t = blockIdx.x; t < nT; t += gridDim.x) {
    const int e0 = t << 6;
    const int ne = min(64, E_N - e0);
    __syncthreads();
    for (int idx = tid; idx < ne * 32; idx += 256) {
      const int e  = idx >> 5;
      const int hq = (idx & 31) << 2;
      const float4 v = *(const float4*)(hyper + (size_t)(e0 + e) * 128 + hq);
      *(float4*)&sHy[e * 132 + hq] = v;
    }
    __syncthreads();
    float acc[16];
    #pragma unroll
    for (int i = 0; i < 16; ++i) acc[i] = 0.f;
    const float* HEw = HEt + waveS * 16;
    for (int hb = 0; hb < 32; ++hb) {
      const float4 hv = *(const float4*)&sHy[lane * 132 + (hb << 2)];
      const float hvv[4] = {hv.x, hv.y, hv.z, hv.w};
      #pragma unroll
      for (int q = 0; q < 4; ++q) {
        const float* hew = HEw + (hb * 4 + q) * 64;
        const float hq = hvv[q];
        #pragma unroll
        for (int i = 0; i < 16; ++i) acc[i] += hq * hew[i];
      }
    }
    if (lane < ne) {
      float* ep = edge + (size_t)(e0 + lane) * 64 + waveS * 16;
      #pragma unroll
      for (int qq = 0; qq < 4; ++qq) {
        float4 r = *(const float4*)(ep + qq * 4);
        r.x = leaky(acc[qq * 4 + 0]) + r.x;
        r.y = leaky(acc[qq * 4 + 1]) + r.y;
        r.z = leaky(acc[qq * 4 + 2]) + r.z;
        r.w = leaky(acc[qq * 4 + 3]) + r.w;
        *(float4*)(ep + qq * 4) = r;
      }
    }
  }
}

// -------- segment-sum scatter: wave per edge --------
__global__ void scatterKernel(const float* __restrict__ edge,
                              const int* __restrict__ src, const int* __restrict__ tgt,
                              float* __restrict__ out) {
  const int lane = threadIdx.x & 63;
  const int gw0 = blockIdx.x * 4 + (threadIdx.x >> 6);
  const int nW  = gridDim.x * 4;
  for (int e = gw0; e < E_N; e += nW) {
    const float v = edge[(size_t)e * 64 + lane];
    const int s = src[e];
    const int t = tgt[e];
    atomicAdd(out + (size_t)s * 64 + lane, v);
    atomicAdd(out + (size_t)USER_N * 64 + (size_t)t * 64 + lane, v);
  }
}

extern "C" void kernel_launch(void* const* d_in, const int* in_sizes, int n_in,
                              void* d_out, int out_size, void* d_ws, size_t ws_size,
                              hipStream_t stream) {
  const float* uE    = (const float*)d_in[0];
  const float* iE    = (const float*)d_in[1];
  const float* T     = (const float*)d_in[2];
  const float* hyper = (const float*)d_in[3];
  const int*   src   = (const int*)d_in[4];
  const int*   tgt   = (const int*)d_in[5];
  const int*   val   = (const int*)d_in[6];
  float* out = (float*)d_out;
  float* ws  = (float*)d_ws;

  float* edge     = ws;                        // 6,400,000 floats
  float* partials = ws + 6400000;              // NB_ACC * 8192 = 4,194,304 floats
  float* HEt      = ws + 6400000 + 4194304;    // 8192 floats

  zeroKernel<<<512, 256, 0, stream>>>((float4*)out, out_size / 4);
  stageAKernel<<<512, 256, 0, stream>>>(uE, iE, T, src, tgt, val, edge);
  for (int layer = 0; layer < 2; ++layer) {
    hyperAccumKernel<<<NB_ACC, 256, 0, stream>>>(edge, hyper, partials);
    reduceHEKernel<<<32, 256, 0, stream>>>(partials, HEt);
    nodeUpdateKernel<<<512, 256, 0, stream>>>(HEt, hyper, edge);
  }
  scatterKernel<<<512, 256, 0, stream>>>(edge, src, tgt, out);
}

// Round 2
// 399.349 us; speedup vs baseline: 1.3511x; 1.3511x over previous
//
#include <hip/hip_runtime.h>

#define E_N     100000
#define USER_N  100000
#define NB_ACC  512

__device__ __forceinline__ float leaky(float x) { return x > 0.f ? x : 0.5f * x; }

// -------- zero d_out --------
__global__ void zeroKernel(float4* __restrict__ p, int n4) {
  int i = blockIdx.x * blockDim.x + threadIdx.x;
  const int stride = gridDim.x * blockDim.x;
  const float4 z = make_float4(0.f, 0.f, 0.f, 0.f);
  for (; i < n4; i += stride) p[i] = z;
}

// -------- Stage A: edge[e,k] = (sum_d uE[src[e],d] * T[val[e],d,k]) * iE[tgt[e],k] --------
__global__ void stageAKernel(const float* __restrict__ uE, const float* __restrict__ iE,
                             const float* __restrict__ T,
                             const int* __restrict__ src, const int* __restrict__ tgt,
                             const int* __restrict__ val,
                             float* __restrict__ edge) {
  __shared__ float sSrc[4 * 4 * 68];
  const int tid  = threadIdx.x;
  const int lane = tid & 63;
  const int wave = __builtin_amdgcn_readfirstlane(tid >> 6);
  const int j    = lane >> 4;
  const int l16  = lane & 15;
  float* sS = sSrc + wave * (4 * 68);
  const int nGroups = E_N / 4;
  const int gw0 = blockIdx.x * 4 + wave;
  const int nW  = gridDim.x * 4;
  for (int g = gw0; g < nGroups; g += nW) {
    const int e0 = g * 4;
    const int srcj = src[e0 + j];
    #pragma unroll
    for (int it = 0; it < 4; ++it) {
      const int d = l16 + 16 * it;
      sS[j * 68 + d] = uE[(size_t)srcj * 64 + d];
    }
    const int vj = val[e0 + j];
    const int tj = tgt[e0 + j];
    const float4* Tp = (const float4*)(T + (size_t)vj * 4096) + l16;
    float4 acc = make_float4(0.f, 0.f, 0.f, 0.f);
    #pragma unroll 8
    for (int d = 0; d < 64; ++d) {
      const float4 t4 = Tp[d * 16];
      const float  sv = sS[j * 68 + d];
      acc.x += sv * t4.x; acc.y += sv * t4.y;
      acc.z += sv * t4.z; acc.w += sv * t4.w;
    }
    const float4 iv = *(const float4*)(iE + (size_t)tj * 64 + l16 * 4);
    float4 r;
    r.x = acc.x * iv.x; r.y = acc.y * iv.y;
    r.z = acc.z * iv.z; r.w = acc.w * iv.w;
    *(float4*)(edge + (size_t)(e0 + j) * 64 + l16 * 4) = r;
  }
}

// -------- einsum1: C[d,h] += edge[e,d]*hyper[e,h], per-block partials --------
// block = contiguous edge chunk; LDS-staged 32-edge tiles; thread tile 4d x 8h.
__global__ void __launch_bounds__(256) hyperAccumKernel(const float* __restrict__ edge,
                                                        const float* __restrict__ hyper,
                                                        float* __restrict__ partials) {
  __shared__ float sE[32 * 68];
  __shared__ float sH[32 * 132];
  const int tid = threadIdx.x;
  const int d0  = (tid & 15) * 4;
  const int h0  = (tid >> 4) * 8;
  float acc[4][8];
  #pragma unroll
  for (int j = 0; j < 4; ++j)
    #pragma unroll
    for (int i = 0; i < 8; ++i) acc[j][i] = 0.f;

  const int chunk = (E_N + NB_ACC - 1) / NB_ACC;  // 196
  const int start = blockIdx.x * chunk;
  const int end   = min(start + chunk, E_N);

  for (int base = start; base < end; base += 32) {
    __syncthreads();
    #pragma unroll
    for (int r = 0; r < 2; ++r) {
      const int idx = r * 256 + tid;
      const int e = idx >> 4, dq = (idx & 15) * 4;
      float4 v = make_float4(0.f, 0.f, 0.f, 0.f);
      if (base + e < end) v = *(const float4*)(edge + (size_t)(base + e) * 64 + dq);
      *(float4*)&sE[e * 68 + dq] = v;
    }
    #pragma unroll
    for (int r = 0; r < 4; ++r) {
      const int idx = r * 256 + tid;
      const int e = idx >> 5, hq = (idx & 31) * 4;
      float4 v = make_float4(0.f, 0.f, 0.f, 0.f);
      if (base + e < end) v = *(const float4*)(hyper + (size_t)(base + e) * 128 + hq);
      *(float4*)&sH[e * 132 + hq] = v;
    }
    __syncthreads();
    #pragma unroll 4
    for (int e = 0; e < 32; ++e) {
      const float4 ed = *(const float4*)&sE[e * 68 + d0];
      const float4 ha = *(const float4*)&sH[e * 132 + h0];
      const float4 hb = *(const float4*)&sH[e * 132 + h0 + 4];
      const float ev[4] = {ed.x, ed.y, ed.z, ed.w};
      const float hv[8] = {ha.x, ha.y, ha.z, ha.w, hb.x, hb.y, hb.z, hb.w};
      #pragma unroll
      for (int j = 0; j < 4; ++j)
        #pragma unroll
        for (int i = 0; i < 8; ++i) acc[j][i] += ev[j] * hv[i];
    }
  }
  float* pp = partials + (size_t)blockIdx.x * 8192;
  #pragma unroll
  for (int i = 0; i < 8; ++i) {
    const float4 v = make_float4(acc[0][i], acc[1][i], acc[2][i], acc[3][i]);
    *(float4*)(pp + (h0 + i) * 64 + d0) = v;
  }
}

// -------- reduce stage 1: sum 64 partial rows -> partial2[8][8192] --------
__global__ void reduce1Kernel(const float* __restrict__ partials, float* __restrict__ partial2) {
  const int i = blockIdx.x * 256 + threadIdx.x;   // gridDim.x = 32
  const int y = blockIdx.y;                       // 0..7
  const float* p = partials + (size_t)y * 64 * 8192 + i;
  float s0 = 0.f, s1 = 0.f, s2 = 0.f, s3 = 0.f;
  #pragma unroll 4
  for (int b = 0; b < 64; b += 4) {
    s0 += p[(size_t)(b + 0) * 8192];
    s1 += p[(size_t)(b + 1) * 8192];
    s2 += p[(size_t)(b + 2) * 8192];
    s3 += p[(size_t)(b + 3) * 8192];
  }
  partial2[y * 8192 + i] = (s0 + s1) + (s2 + s3);
}

// -------- reduce stage 2 + leaky -> HEt[h*64+d] --------
__global__ void reduce2Kernel(const float* __restrict__ partial2, float* __restrict__ HEt) {
  const int i = blockIdx.x * 256 + threadIdx.x;   // 32 blocks
  float s = 0.f;
  #pragma unroll
  for (int y = 0; y < 8; ++y) s += partial2[y * 8192 + i];
  HEt[i] = leaky(s);
}

// -------- einsum2 + residual: edge[e,d] += act(sum_h hyper[e,h]*HEt[h,d]) --------
// full HEt (32KB) in LDS; 64-edge hyper tiles in LDS; thread tile 4e x 4d.
__global__ void __launch_bounds__(256) nodeUpdateKernel(const float* __restrict__ HEt,
                                                        const float* __restrict__ hyper,
                                                        float* __restrict__ edge) {
  __shared__ float sHE[8192];
  __shared__ float sHy[64 * 132];
  const int tid = threadIdx.x;
  #pragma unroll
  for (int r = 0; r < 8; ++r) {
    const int idx = r * 256 + tid;
    *(float4*)&sHE[idx * 4] = *(const float4*)(HEt + idx * 4);
  }
  const int e0 = (tid >> 4) * 4;
  const int d0 = (tid & 15) * 4;
  const int nT = (E_N + 63) >> 6;  // 1563
  for (int t = blockIdx.x; t < nT; t += gridDim.x) {
    const int ge0 = t << 6;
    __syncthreads();
    #pragma unroll
    for (int r = 0; r < 8; ++r) {
      const int idx = r * 256 + tid;
      const int e = idx >> 5, hq = (idx & 31) * 4;
      float4 v = make_float4(0.f, 0.f, 0.f, 0.f);
      if (ge0 + e < E_N) v = *(const float4*)(hyper + (size_t)(ge0 + e) * 128 + hq);
      *(float4*)&sHy[e * 132 + hq] = v;
    }
    __syncthreads();
    float acc[4][4];
    #pragma unroll
    for (int j = 0; j < 4; ++j)
      #pragma unroll
      for (int k = 0; k < 4; ++k) acc[j][k] = 0.f;
    #pragma unroll 4
    for (int hb = 0; hb < 32; ++hb) {
      float4 hv4[4], he4[4];
      #pragma unroll
      for (int j = 0; j < 4; ++j) hv4[j] = *(const float4*)&sHy[(e0 + j) * 132 + hb * 4];
      #pragma unroll
      for (int q = 0; q < 4; ++q) he4[q] = *(const float4*)&sHE[(hb * 4 + q) * 64 + d0];
      #pragma unroll
      for (int j = 0; j < 4; ++j) {
        const float hj[4] = {hv4[j].x, hv4[j].y, hv4[j].z, hv4[j].w};
        #pragma unroll
        for (int q = 0; q < 4; ++q) {
          const float hq = hj[q];
          acc[j][0] += hq * he4[q].x;
          acc[j][1] += hq * he4[q].y;
          acc[j][2] += hq * he4[q].z;
          acc[j][3] += hq * he4[q].w;
        }
      }
    }
    #pragma unroll
    for (int j = 0; j < 4; ++j) {
      const int ge = ge0 + e0 + j;
      if (ge < E_N) {
        float* ep = edge + (size_t)ge * 64 + d0;
        float4 r = *(const float4*)ep;
        r.x += leaky(acc[j][0]);
        r.y += leaky(acc[j][1]);
        r.z += leaky(acc[j][2]);
        r.w += leaky(acc[j][3]);
        *(float4*)ep = r;
      }
    }
  }
}

// -------- segment-sum scatter: wave per edge --------
__global__ void scatterKernel(const float* __restrict__ edge,
                              const int* __restrict__ src, const int* __restrict__ tgt,
                              float* __restrict__ out) {
  const int lane = threadIdx.x & 63;
  const int gw0 = blockIdx.x * 4 + (threadIdx.x >> 6);
  const int nW  = gridDim.x * 4;
  for (int e = gw0; e < E_N; e += nW) {
    const float v = edge[(size_t)e * 64 + lane];
    const int s = src[e];
    const int t = tgt[e];
    atomicAdd(out + (size_t)s * 64 + lane, v);
    atomicAdd(out + (size_t)USER_N * 64 + (size_t)t * 64 + lane, v);
  }
}

extern "C" void kernel_launch(void* const* d_in, const int* in_sizes, int n_in,
                              void* d_out, int out_size, void* d_ws, size_t ws_size,
                              hipStream_t stream) {
  const float* uE    = (const float*)d_in[0];
  const float* iE    = (const float*)d_in[1];
  const float* T     = (const float*)d_in[2];
  const float* hyper = (const float*)d_in[3];
  const int*   src   = (const int*)d_in[4];
  const int*   tgt   = (const int*)d_in[5];
  const int*   val   = (const int*)d_in[6];
  float* out = (float*)d_out;
  float* ws  = (float*)d_ws;

  float* edge     = ws;                                  // 6,400,000 floats
  float* partials = ws + 6400000;                        // 512*8192 = 4,194,304
  float* partial2 = ws + 6400000 + 4194304;              // 8*8192 = 65,536
  float* HEt      = ws + 6400000 + 4194304 + 65536;      // 8192

  zeroKernel<<<512, 256, 0, stream>>>((float4*)out, out_size / 4);
  stageAKernel<<<512, 256, 0, stream>>>(uE, iE, T, src, tgt, val, edge);
  for (int layer = 0; layer < 2; ++layer) {
    hyperAccumKernel<<<NB_ACC, 256, 0, stream>>>(edge, hyper, partials);
    reduce1Kernel<<<dim3(32, 8), 256, 0, stream>>>(partials, partial2);
    reduce2Kernel<<<32, 256, 0, stream>>>(partial2, HEt);
    nodeUpdateKernel<<<512, 256, 0, stream>>>(HEt, hyper, edge);
  }
  scatterKernel<<<512, 256, 0, stream>>>(edge, src, tgt, out);
}

// Round 3
// 397.039 us; speedup vs baseline: 1.3590x; 1.0058x over previous
//
#include <hip/hip_runtime.h>

#define E_N     100000
#define USER_N  100000
#define NB_ACC  512

__device__ __forceinline__ float leaky(float x) { return x > 0.f ? x : 0.5f * x; }

// -------- zero d_out --------
__global__ void zeroKernel(float4* __restrict__ p, int n4) {
  int i = blockIdx.x * blockDim.x + threadIdx.x;
  const int stride = gridDim.x * blockDim.x;
  const float4 z = make_float4(0.f, 0.f, 0.f, 0.f);
  for (; i < n4; i += stride) p[i] = z;
}

// -------- Stage A: edge[e,k] = (sum_d uE[src[e],d] * T[val[e],d,k]) * iE[tgt[e],k] --------
// one 4-edge group per wave; full occupancy grid (6250 blocks = 25000 waves)
__global__ void __launch_bounds__(256) stageAKernel(const float* __restrict__ uE,
                             const float* __restrict__ iE,
                             const float* __restrict__ T,
                             const int* __restrict__ src, const int* __restrict__ tgt,
                             const int* __restrict__ val,
                             float* __restrict__ edge) {
  __shared__ float sSrc[4 * 4 * 68];
  const int tid  = threadIdx.x;
  const int lane = tid & 63;
  const int wave = tid >> 6;
  const int j    = lane >> 4;
  const int l16  = lane & 15;
  float* sS = sSrc + wave * (4 * 68);
  const int g = blockIdx.x * 4 + wave;        // one group per wave
  if (g >= E_N / 4) return;
  const int e0 = g * 4;
  const int srcj = src[e0 + j];
  const int vj   = val[e0 + j];
  const int tj   = tgt[e0 + j];
  #pragma unroll
  for (int it = 0; it < 4; ++it) {
    const int d = l16 + 16 * it;
    sS[j * 68 + d] = uE[(size_t)srcj * 64 + d];
  }
  const float4* Tp = (const float4*)(T + (size_t)vj * 4096) + l16;
  float4 acc = make_float4(0.f, 0.f, 0.f, 0.f);
  #pragma unroll
  for (int db = 0; db < 64; db += 4) {
    const float4 sv = *(const float4*)&sS[j * 68 + db];   // ds_read_b128, conflict-free
    const float4 t0 = Tp[(db + 0) * 16];
    const float4 t1 = Tp[(db + 1) * 16];
    const float4 t2 = Tp[(db + 2) * 16];
    const float4 t3 = Tp[(db + 3) * 16];
    acc.x += sv.x * t0.x; acc.y += sv.x * t0.y; acc.z += sv.x * t0.z; acc.w += sv.x * t0.w;
    acc.x += sv.y * t1.x; acc.y += sv.y * t1.y; acc.z += sv.y * t1.z; acc.w += sv.y * t1.w;
    acc.x += sv.z * t2.x; acc.y += sv.z * t2.y; acc.z += sv.z * t2.z; acc.w += sv.z * t2.w;
    acc.x += sv.w * t3.x; acc.y += sv.w * t3.y; acc.z += sv.w * t3.z; acc.w += sv.w * t3.w;
  }
  const float4 iv = *(const float4*)(iE + (size_t)tj * 64 + l16 * 4);
  float4 r;
  r.x = acc.x * iv.x; r.y = acc.y * iv.y;
  r.z = acc.z * iv.z; r.w = acc.w * iv.w;
  *(float4*)(edge + (size_t)(e0 + j) * 64 + l16 * 4) = r;
}

// -------- einsum1: C[d,h] += edge[e,d]*hyper[e,h], per-block partials --------
__global__ void __launch_bounds__(256) hyperAccumKernel(const float* __restrict__ edge,
                                                        const float* __restrict__ hyper,
                                                        float* __restrict__ partials) {
  __shared__ float sE[32 * 68];
  __shared__ float sH[32 * 132];
  const int tid = threadIdx.x;
  const int d0  = (tid & 15) * 4;
  const int h0  = (tid >> 4) * 8;
  float acc[4][8];
  #pragma unroll
  for (int j = 0; j < 4; ++j)
    #pragma unroll
    for (int i = 0; i < 8; ++i) acc[j][i] = 0.f;

  const int chunk = (E_N + NB_ACC - 1) / NB_ACC;  // 196
  const int start = blockIdx.x * chunk;
  const int end   = min(start + chunk, E_N);

  for (int base = start; base < end; base += 32) {
    __syncthreads();
    #pragma unroll
    for (int r = 0; r < 2; ++r) {
      const int idx = r * 256 + tid;
      const int e = idx >> 4, dq = (idx & 15) * 4;
      float4 v = make_float4(0.f, 0.f, 0.f, 0.f);
      if (base + e < end) v = *(const float4*)(edge + (size_t)(base + e) * 64 + dq);
      *(float4*)&sE[e * 68 + dq] = v;
    }
    #pragma unroll
    for (int r = 0; r < 4; ++r) {
      const int idx = r * 256 + tid;
      const int e = idx >> 5, hq = (idx & 31) * 4;
      float4 v = make_float4(0.f, 0.f, 0.f, 0.f);
      if (base + e < end) v = *(const float4*)(hyper + (size_t)(base + e) * 128 + hq);
      *(float4*)&sH[e * 132 + hq] = v;
    }
    __syncthreads();
    #pragma unroll 4
    for (int e = 0; e < 32; ++e) {
      const float4 ed = *(const float4*)&sE[e * 68 + d0];
      const float4 ha = *(const float4*)&sH[e * 132 + h0];
      const float4 hb = *(const float4*)&sH[e * 132 + h0 + 4];
      const float ev[4] = {ed.x, ed.y, ed.z, ed.w};
      const float hv[8] = {ha.x, ha.y, ha.z, ha.w, hb.x, hb.y, hb.z, hb.w};
      #pragma unroll
      for (int j = 0; j < 4; ++j)
        #pragma unroll
        for (int i = 0; i < 8; ++i) acc[j][i] += ev[j] * hv[i];
    }
  }
  float* pp = partials + (size_t)blockIdx.x * 8192;
  #pragma unroll
  for (int i = 0; i < 8; ++i) {
    const float4 v = make_float4(acc[0][i], acc[1][i], acc[2][i], acc[3][i]);
    *(float4*)(pp + (h0 + i) * 64 + d0) = v;
  }
}

// -------- reduce stage 1: sum 64 partial rows -> partial2[8][8192] --------
__global__ void reduce1Kernel(const float* __restrict__ partials, float* __restrict__ partial2) {
  const int i = blockIdx.x * 256 + threadIdx.x;   // gridDim.x = 32
  const int y = blockIdx.y;                       // 0..7
  const float* p = partials + (size_t)y * 64 * 8192 + i;
  float s0 = 0.f, s1 = 0.f, s2 = 0.f, s3 = 0.f;
  #pragma unroll 4
  for (int b = 0; b < 64; b += 4) {
    s0 += p[(size_t)(b + 0) * 8192];
    s1 += p[(size_t)(b + 1) * 8192];
    s2 += p[(size_t)(b + 2) * 8192];
    s3 += p[(size_t)(b + 3) * 8192];
  }
  partial2[y * 8192 + i] = (s0 + s1) + (s2 + s3);
}

// -------- reduce stage 2 + leaky -> HEt[h*64+d] --------
__global__ void reduce2Kernel(const float* __restrict__ partial2, float* __restrict__ HEt) {
  const int i = blockIdx.x * 256 + threadIdx.x;   // 32 blocks
  float s = 0.f;
  #pragma unroll
  for (int y = 0; y < 8; ++y) s += partial2[y * 8192 + i];
  HEt[i] = leaky(s);
}

// -------- einsum2 + residual: edge[e,d] += act(sum_h hyper[e,h]*HEt[h,d]) --------
__global__ void __launch_bounds__(256) nodeUpdateKernel(const float* __restrict__ HEt,
                                                        const float* __restrict__ hyper,
                                                        float* __restrict__ edge) {
  __shared__ float sHE[8192];
  __shared__ float sHy[64 * 132];
  const int tid = threadIdx.x;
  #pragma unroll
  for (int r = 0; r < 8; ++r) {
    const int idx = r * 256 + tid;
    *(float4*)&sHE[idx * 4] = *(const float4*)(HEt + idx * 4);
  }
  const int e0 = (tid >> 4) * 4;
  const int d0 = (tid & 15) * 4;
  const int nT = (E_N + 63) >> 6;  // 1563
  for (int t = blockIdx.x; t < nT; t += gridDim.x) {
    const int ge0 = t << 6;
    __syncthreads();
    #pragma unroll
    for (int r = 0; r < 8; ++r) {
      const int idx = r * 256 + tid;
      const int e = idx >> 5, hq = (idx & 31) * 4;
      float4 v = make_float4(0.f, 0.f, 0.f, 0.f);
      if (ge0 + e < E_N) v = *(const float4*)(hyper + (size_t)(ge0 + e) * 128 + hq);
      *(float4*)&sHy[e * 132 + hq] = v;
    }
    __syncthreads();
    float acc[4][4];
    #pragma unroll
    for (int j = 0; j < 4; ++j)
      #pragma unroll
      for (int k = 0; k < 4; ++k) acc[j][k] = 0.f;
    #pragma unroll 4
    for (int hb = 0; hb < 32; ++hb) {
      float4 hv4[4], he4[4];
      #pragma unroll
      for (int j = 0; j < 4; ++j) hv4[j] = *(const float4*)&sHy[(e0 + j) * 132 + hb * 4];
      #pragma unroll
      for (int q = 0; q < 4; ++q) he4[q] = *(const float4*)&sHE[(hb * 4 + q) * 64 + d0];
      #pragma unroll
      for (int j = 0; j < 4; ++j) {
        const float hj[4] = {hv4[j].x, hv4[j].y, hv4[j].z, hv4[j].w};
        #pragma unroll
        for (int q = 0; q < 4; ++q) {
          const float hq = hj[q];
          acc[j][0] += hq * he4[q].x;
          acc[j][1] += hq * he4[q].y;
          acc[j][2] += hq * he4[q].z;
          acc[j][3] += hq * he4[q].w;
        }
      }
    }
    #pragma unroll
    for (int j = 0; j < 4; ++j) {
      const int ge = ge0 + e0 + j;
      if (ge < E_N) {
        float* ep = edge + (size_t)ge * 64 + d0;
        float4 r = *(const float4*)ep;
        r.x += leaky(acc[j][0]);
        r.y += leaky(acc[j][1]);
        r.z += leaky(acc[j][2]);
        r.w += leaky(acc[j][3]);
        *(float4*)ep = r;
      }
    }
  }
}

// -------- segment-sum scatter: wave per edge --------
__global__ void scatterKernel(const float* __restrict__ edge,
                              const int* __restrict__ src, const int* __restrict__ tgt,
                              float* __restrict__ out) {
  const int lane = threadIdx.x & 63;
  const int gw0 = blockIdx.x * 4 + (threadIdx.x >> 6);
  const int nW  = gridDim.x * 4;
  for (int e = gw0; e < E_N; e += nW) {
    const float v = edge[(size_t)e * 64 + lane];
    const int s = src[e];
    const int t = tgt[e];
    atomicAdd(out + (size_t)s * 64 + lane, v);
    atomicAdd(out + (size_t)USER_N * 64 + (size_t)t * 64 + lane, v);
  }
}

extern "C" void kernel_launch(void* const* d_in, const int* in_sizes, int n_in,
                              void* d_out, int out_size, void* d_ws, size_t ws_size,
                              hipStream_t stream) {
  const float* uE    = (const float*)d_in[0];
  const float* iE    = (const float*)d_in[1];
  const float* T     = (const float*)d_in[2];
  const float* hyper = (const float*)d_in[3];
  const int*   src   = (const int*)d_in[4];
  const int*   tgt   = (const int*)d_in[5];
  const int*   val   = (const int*)d_in[6];
  float* out = (float*)d_out;
  float* ws  = (float*)d_ws;

  float* edge     = ws;                                  // 6,400,000 floats
  float* partials = ws + 6400000;                        // 512*8192 = 4,194,304
  float* partial2 = ws + 6400000 + 4194304;              // 8*8192 = 65,536
  float* HEt      = ws + 6400000 + 4194304 + 65536;      // 8192

  zeroKernel<<<2048, 256, 0, stream>>>((float4*)out, out_size / 4);
  stageAKernel<<<6250, 256, 0, stream>>>(uE, iE, T, src, tgt, val, edge);
  for (int layer = 0; layer < 2; ++layer) {
    hyperAccumKernel<<<NB_ACC, 256, 0, stream>>>(edge, hyper, partials);
    reduce1Kernel<<<dim3(32, 8), 256, 0, stream>>>(partials, partial2);
    reduce2Kernel<<<32, 256, 0, stream>>>(partial2, HEt);
    nodeUpdateKernel<<<512, 256, 0, stream>>>(HEt, hyper, edge);
  }
  scatterKernel<<<3125, 256, 0, stream>>>(edge, src, tgt, out);
}

// Round 4
// 382.441 us; speedup vs baseline: 1.4108x; 1.0382x over previous
//
#include <hip/hip_runtime.h>

#define E_N     100000
#define USER_N  100000
#define NB_ACC  512
#define BIN_CAP 16384

__device__ __forceinline__ float leaky(float x) { return x > 0.f ? x : 0.5f * x; }

// -------- zero d_out --------
__global__ void zeroKernel(float4* __restrict__ p, int n4) {
  int i = blockIdx.x * blockDim.x + threadIdx.x;
  const int stride = gridDim.x * blockDim.x;
  const float4 z = make_float4(0.f, 0.f, 0.f, 0.f);
  for (; i < n4; i += stride) p[i] = z;
}

// -------- binning: perm[v*BIN_CAP + slot] = edge index, cnt[v] = bin size --------
__global__ void initCountKernel(int* __restrict__ cnt) {
  if (threadIdx.x < 8) cnt[threadIdx.x] = 0;
}

__global__ void binKernel(const int* __restrict__ val, int* __restrict__ perm,
                          int* __restrict__ cnt) {
  __shared__ int lh[8], lbase[8];
  const int tid = threadIdx.x;
  if (tid < 8) lh[tid] = 0;
  __syncthreads();
  const int e = blockIdx.x * 256 + tid;
  int v = -1, slot = 0;
  if (e < E_N) { v = val[e]; slot = atomicAdd(&lh[v], 1); }
  __syncthreads();
  if (tid < 8) lbase[tid] = atomicAdd(&cnt[tid], lh[tid]);
  __syncthreads();
  if (v >= 0) perm[v * BIN_CAP + lbase[v] + slot] = e;
}

// -------- Stage A as 8 binned GEMMs: C[e,k] = (uE[src[e],:] @ T[v]) * iE[tgt[e],k] --------
// block = one 64-edge tile of one etype; T[v] + gathered uE tile in LDS; 4e x 4k thread tile.
__global__ void __launch_bounds__(256) stageAGemmKernel(
    const float* __restrict__ uE, const float* __restrict__ iE, const float* __restrict__ T,
    const int* __restrict__ src, const int* __restrict__ tgt,
    const int* __restrict__ perm, const int* __restrict__ cnt,
    float* __restrict__ edge) {
  __shared__ float sT[64 * 68];
  __shared__ float sA[64 * 68];
  const int v  = blockIdx.y;
  const int nE = min(cnt[v], BIN_CAP);
  const int t0 = blockIdx.x * 64;
  if (t0 >= nE) return;
  const int tid = threadIdx.x;
  // T[v] -> LDS (coalesced)
  #pragma unroll
  for (int r = 0; r < 4; ++r) {
    const int idx = r * 256 + tid;
    const int d = idx >> 4, kq = (idx & 15) * 4;
    *(float4*)&sT[d * 68 + kq] = *(const float4*)(T + (size_t)v * 4096 + d * 64 + kq);
  }
  // gathered uE tile -> LDS
  #pragma unroll
  for (int r = 0; r < 4; ++r) {
    const int idx = r * 256 + tid;
    const int e = idx >> 4, dq = (idx & 15) * 4;
    float4 x = make_float4(0.f, 0.f, 0.f, 0.f);
    if (t0 + e < nE) {
      const int eIdx = perm[v * BIN_CAP + t0 + e];
      const int s = src[eIdx];
      x = *(const float4*)(uE + (size_t)s * 64 + dq);
    }
    *(float4*)&sA[e * 68 + dq] = x;
  }
  __syncthreads();
  const int e0 = (tid >> 4) * 4;
  const int k0 = (tid & 15) * 4;
  float acc[4][4];
  #pragma unroll
  for (int j = 0; j < 4; ++j)
    #pragma unroll
    for (int k = 0; k < 4; ++k) acc[j][k] = 0.f;
  #pragma unroll 4
  for (int db = 0; db < 16; ++db) {
    float4 a4[4], t4[4];
    #pragma unroll
    for (int j = 0; j < 4; ++j) a4[j] = *(const float4*)&sA[(e0 + j) * 68 + db * 4];
    #pragma unroll
    for (int q = 0; q < 4; ++q) t4[q] = *(const float4*)&sT[(db * 4 + q) * 68 + k0];
    #pragma unroll
    for (int j = 0; j < 4; ++j) {
      const float aj[4] = {a4[j].x, a4[j].y, a4[j].z, a4[j].w};
      #pragma unroll
      for (int q = 0; q < 4; ++q) {
        const float a = aj[q];
        acc[j][0] += a * t4[q].x;
        acc[j][1] += a * t4[q].y;
        acc[j][2] += a * t4[q].z;
        acc[j][3] += a * t4[q].w;
      }
    }
  }
  // epilogue: * iE[tgt], scatter-store to edge[eIdx]
  #pragma unroll
  for (int j = 0; j < 4; ++j) {
    const int et = t0 + e0 + j;
    if (et < nE) {
      const int eIdx = perm[v * BIN_CAP + et];
      const int tj = tgt[eIdx];
      const float4 iv = *(const float4*)(iE + (size_t)tj * 64 + k0);
      float4 r;
      r.x = acc[j][0] * iv.x; r.y = acc[j][1] * iv.y;
      r.z = acc[j][2] * iv.z; r.w = acc[j][3] * iv.w;
      *(float4*)(edge + (size_t)eIdx * 64 + k0) = r;
    }
  }
}

// -------- einsum1: C[d,h] += edge[e,d]*hyper[e,h], per-block partials --------
__global__ void __launch_bounds__(256) hyperAccumKernel(const float* __restrict__ edge,
                                                        const float* __restrict__ hyper,
                                                        float* __restrict__ partials) {
  __shared__ float sE[32 * 68];
  __shared__ float sH[32 * 132];
  const int tid = threadIdx.x;
  const int d0  = (tid & 15) * 4;
  const int h0  = (tid >> 4) * 8;
  float acc[4][8];
  #pragma unroll
  for (int j = 0; j < 4; ++j)
    #pragma unroll
    for (int i = 0; i < 8; ++i) acc[j][i] = 0.f;

  const int chunk = (E_N + NB_ACC - 1) / NB_ACC;  // 196
  const int start = blockIdx.x * chunk;
  const int end   = min(start + chunk, E_N);

  for (int base = start; base < end; base += 32) {
    __syncthreads();
    #pragma unroll
    for (int r = 0; r < 2; ++r) {
      const int idx = r * 256 + tid;
      const int e = idx >> 4, dq = (idx & 15) * 4;
      float4 v = make_float4(0.f, 0.f, 0.f, 0.f);
      if (base + e < end) v = *(const float4*)(edge + (size_t)(base + e) * 64 + dq);
      *(float4*)&sE[e * 68 + dq] = v;
    }
    #pragma unroll
    for (int r = 0; r < 4; ++r) {
      const int idx = r * 256 + tid;
      const int e = idx >> 5, hq = (idx & 31) * 4;
      float4 v = make_float4(0.f, 0.f, 0.f, 0.f);
      if (base + e < end) v = *(const float4*)(hyper + (size_t)(base + e) * 128 + hq);
      *(float4*)&sH[e * 132 + hq] = v;
    }
    __syncthreads();
    #pragma unroll 4
    for (int e = 0; e < 32; ++e) {
      const float4 ed = *(const float4*)&sE[e * 68 + d0];
      const float4 ha = *(const float4*)&sH[e * 132 + h0];
      const float4 hb = *(const float4*)&sH[e * 132 + h0 + 4];
      const float ev[4] = {ed.x, ed.y, ed.z, ed.w};
      const float hv[8] = {ha.x, ha.y, ha.z, ha.w, hb.x, hb.y, hb.z, hb.w};
      #pragma unroll
      for (int j = 0; j < 4; ++j)
        #pragma unroll
        for (int i = 0; i < 8; ++i) acc[j][i] += ev[j] * hv[i];
    }
  }
  float* pp = partials + (size_t)blockIdx.x * 8192;
  #pragma unroll
  for (int i = 0; i < 8; ++i) {
    const float4 v = make_float4(acc[0][i], acc[1][i], acc[2][i], acc[3][i]);
    *(float4*)(pp + (h0 + i) * 64 + d0) = v;
  }
}

// -------- reduce stage 1: sum 64 partial rows -> partial2[8][8192] --------
__global__ void reduce1Kernel(const float* __restrict__ partials, float* __restrict__ partial2) {
  const int i = blockIdx.x * 256 + threadIdx.x;   // gridDim.x = 32
  const int y = blockIdx.y;                       // 0..7
  const float* p = partials + (size_t)y * 64 * 8192 + i;
  float s0 = 0.f, s1 = 0.f, s2 = 0.f, s3 = 0.f;
  #pragma unroll 4
  for (int b = 0; b < 64; b += 4) {
    s0 += p[(size_t)(b + 0) * 8192];
    s1 += p[(size_t)(b + 1) * 8192];
    s2 += p[(size_t)(b + 2) * 8192];
    s3 += p[(size_t)(b + 3) * 8192];
  }
  partial2[y * 8192 + i] = (s0 + s1) + (s2 + s3);
}

// -------- reduce stage 2 + leaky -> HEt[h*64+d] --------
__global__ void reduce2Kernel(const float* __restrict__ partial2, float* __restrict__ HEt) {
  const int i = blockIdx.x * 256 + threadIdx.x;   // 32 blocks
  float s = 0.f;
  #pragma unroll
  for (int y = 0; y < 8; ++y) s += partial2[y * 8192 + i];
  HEt[i] = leaky(s);
}

// -------- einsum2 + residual: edge[e,d] += act(sum_h hyper[e,h]*HEt[h,d]) --------
__global__ void __launch_bounds__(256) nodeUpdateKernel(const float* __restrict__ HEt,
                                                        const float* __restrict__ hyper,
                                                        float* __restrict__ edge) {
  __shared__ float sHE[8192];
  __shared__ float sHy[64 * 132];
  const int tid = threadIdx.x;
  #pragma unroll
  for (int r = 0; r < 8; ++r) {
    const int idx = r * 256 + tid;
    *(float4*)&sHE[idx * 4] = *(const float4*)(HEt + idx * 4);
  }
  const int e0 = (tid >> 4) * 4;
  const int d0 = (tid & 15) * 4;
  const int nT = (E_N + 63) >> 6;  // 1563
  for (int t = blockIdx.x; t < nT; t += gridDim.x) {
    const int ge0 = t << 6;
    __syncthreads();
    #pragma unroll
    for (int r = 0; r < 8; ++r) {
      const int idx = r * 256 + tid;
      const int e = idx >> 5, hq = (idx & 31) * 4;
      float4 v = make_float4(0.f, 0.f, 0.f, 0.f);
      if (ge0 + e < E_N) v = *(const float4*)(hyper + (size_t)(ge0 + e) * 128 + hq);
      *(float4*)&sHy[e * 132 + hq] = v;
    }
    __syncthreads();
    float acc[4][4];
    #pragma unroll
    for (int j = 0; j < 4; ++j)
      #pragma unroll
      for (int k = 0; k < 4; ++k) acc[j][k] = 0.f;
    #pragma unroll 4
    for (int hb = 0; hb < 32; ++hb) {
      float4 hv4[4], he4[4];
      #pragma unroll
      for (int j = 0; j < 4; ++j) hv4[j] = *(const float4*)&sHy[(e0 + j) * 132 + hb * 4];
      #pragma unroll
      for (int q = 0; q < 4; ++q) he4[q] = *(const float4*)&sHE[(hb * 4 + q) * 64 + d0];
      #pragma unroll
      for (int j = 0; j < 4; ++j) {
        const float hj[4] = {hv4[j].x, hv4[j].y, hv4[j].z, hv4[j].w};
        #pragma unroll
        for (int q = 0; q < 4; ++q) {
          const float hq = hj[q];
          acc[j][0] += hq * he4[q].x;
          acc[j][1] += hq * he4[q].y;
          acc[j][2] += hq * he4[q].z;
          acc[j][3] += hq * he4[q].w;
        }
      }
    }
    #pragma unroll
    for (int j = 0; j < 4; ++j) {
      const int ge = ge0 + e0 + j;
      if (ge < E_N) {
        float* ep = edge + (size_t)ge * 64 + d0;
        float4 r = *(const float4*)ep;
        r.x += leaky(acc[j][0]);
        r.y += leaky(acc[j][1]);
        r.z += leaky(acc[j][2]);
        r.w += leaky(acc[j][3]);
        *(float4*)ep = r;
      }
    }
  }
}

// -------- segment-sum scatter: wave per edge --------
__global__ void scatterKernel(const float* __restrict__ edge,
                              const int* __restrict__ src, const int* __restrict__ tgt,
                              float* __restrict__ out) {
  const int lane = threadIdx.x & 63;
  const int gw0 = blockIdx.x * 4 + (threadIdx.x >> 6);
  const int nW  = gridDim.x * 4;
  for (int e = gw0; e < E_N; e += nW) {
    const float v = edge[(size_t)e * 64 + lane];
    const int s = src[e];
    const int t = tgt[e];
    atomicAdd(out + (size_t)s * 64 + lane, v);
    atomicAdd(out + (size_t)USER_N * 64 + (size_t)t * 64 + lane, v);
  }
}

extern "C" void kernel_launch(void* const* d_in, const int* in_sizes, int n_in,
                              void* d_out, int out_size, void* d_ws, size_t ws_size,
                              hipStream_t stream) {
  const float* uE    = (const float*)d_in[0];
  const float* iE    = (const float*)d_in[1];
  const float* T     = (const float*)d_in[2];
  const float* hyper = (const float*)d_in[3];
  const int*   src   = (const int*)d_in[4];
  const int*   tgt   = (const int*)d_in[5];
  const int*   val   = (const int*)d_in[6];
  float* out = (float*)d_out;
  float* ws  = (float*)d_ws;

  float* edge     = ws;                                  // 6,400,000 floats
  float* partials = ws + 6400000;                        // 512*8192 = 4,194,304 floats
  float* partial2 = ws + 6400000 + 4194304;              // 8*8192
  float* HEt      = ws + 6400000 + 4194304 + 65536;      // 8192
  // perm/cnt overlay the partials region (dead until hyperAccum runs)
  int* perm = (int*)partials;                            // 8*BIN_CAP = 131072 ints
  int* cnt  = (int*)(partials + 8 * BIN_CAP);            // 8 ints

  initCountKernel<<<1, 64, 0, stream>>>(cnt);
  binKernel<<<(E_N + 255) / 256, 256, 0, stream>>>(val, perm, cnt);
  zeroKernel<<<2048, 256, 0, stream>>>((float4*)out, out_size / 4);
  stageAGemmKernel<<<dim3(BIN_CAP / 64, 8), 256, 0, stream>>>(uE, iE, T, src, tgt, perm, cnt, edge);
  for (int layer = 0; layer < 2; ++layer) {
    hyperAccumKernel<<<NB_ACC, 256, 0, stream>>>(edge, hyper, partials);
    reduce1Kernel<<<dim3(32, 8), 256, 0, stream>>>(partials, partial2);
    reduce2Kernel<<<32, 256, 0, stream>>>(partial2, HEt);
    nodeUpdateKernel<<<512, 256, 0, stream>>>(HEt, hyper, edge);
  }
  scatterKernel<<<3125, 256, 0, stream>>>(edge, src, tgt, out);
}

// Round 5
// 381.117 us; speedup vs baseline: 1.4157x; 1.0035x over previous
//
#include <hip/hip_runtime.h>

#define E_N     100000
#define USER_N  100000
#define NROW    200000
#define NB_ACC  512
#define BIN_CAP 16384
#define NB_SCAN 782   // 782*256 = 200192 >= NROW

__device__ __forceinline__ float leaky(float x) { return x > 0.f ? x : 0.5f * x; }

// -------- init: zero row counts + etype counts --------
__global__ void initCsrKernel(int* __restrict__ cnt, int* __restrict__ cnt8) {
  const int i = blockIdx.x * 256 + threadIdx.x;
  if (i < NROW + 2) cnt[i] = 0;
  if (i < 8) cnt8[i] = 0;
}

// -------- binning by etype + row histogram --------
__global__ void binKernel(const int* __restrict__ val, const int* __restrict__ src,
                          const int* __restrict__ tgt,
                          int* __restrict__ perm, int* __restrict__ permSrc,
                          int* __restrict__ permTgt,
                          int* __restrict__ cnt8, int* __restrict__ cnt) {
  __shared__ int lh[8], lbase[8];
  const int tid = threadIdx.x;
  if (tid < 8) lh[tid] = 0;
  __syncthreads();
  const int e = blockIdx.x * 256 + tid;
  int v = -1, slot = 0, s = 0, t = 0;
  if (e < E_N) {
    v = val[e]; s = src[e]; t = tgt[e];
    slot = atomicAdd(&lh[v], 1);
    atomicAdd(&cnt[s], 1);
    atomicAdd(&cnt[USER_N + t], 1);
  }
  __syncthreads();
  if (tid < 8) lbase[tid] = atomicAdd(&cnt8[tid], lh[tid]);
  __syncthreads();
  if (v >= 0) {
    const int p = v * BIN_CAP + lbase[v] + slot;
    perm[p] = e; permSrc[p] = s; permTgt[p] = t;
  }
}

// -------- scan stage 1: per-block sums --------
__global__ void scanSumsKernel(const int* __restrict__ cnt, int* __restrict__ bsum) {
  __shared__ int sd[256];
  const int tid = threadIdx.x;
  const int i = blockIdx.x * 256 + tid;
  sd[tid] = (i < NROW) ? cnt[i] : 0;
  __syncthreads();
  #pragma unroll
  for (int s = 128; s > 0; s >>= 1) {
    if (tid < s) sd[tid] += sd[tid + s];
    __syncthreads();
  }
  if (tid == 0) bsum[blockIdx.x] = sd[0];
}

// -------- scan stage 2: exclusive scan of block sums (1 block, 1024 thr) --------
__global__ void scanOffsKernel(const int* __restrict__ bsum, int* __restrict__ bOff) {
  __shared__ int sd[1024];
  const int tid = threadIdx.x;
  const int v = (tid < NB_SCAN) ? bsum[tid] : 0;
  sd[tid] = v;
  __syncthreads();
  #pragma unroll
  for (int off = 1; off < 1024; off <<= 1) {
    const int x = (tid >= off) ? sd[tid - off] : 0;
    __syncthreads();
    sd[tid] += x;
    __syncthreads();
  }
  bOff[tid] = sd[tid] - v;   // exclusive
}

// -------- scan stage 3: per-block exclusive scan + offset -> rowStart, rowCur --------
__global__ void scanFinKernel(const int* __restrict__ cnt, const int* __restrict__ bOff,
                              int* __restrict__ rowStart, int* __restrict__ rowCur) {
  __shared__ int sd[256];
  const int tid = threadIdx.x;
  const int i = blockIdx.x * 256 + tid;
  const int c = (i < NROW) ? cnt[i] : 0;
  sd[tid] = c;
  __syncthreads();
  #pragma unroll
  for (int off = 1; off < 256; off <<= 1) {
    const int x = (tid >= off) ? sd[tid - off] : 0;
    __syncthreads();
    sd[tid] += x;
    __syncthreads();
  }
  const int excl = sd[tid] - c;
  const int base = bOff[blockIdx.x];
  if (i < NROW) { rowStart[i] = base + excl; rowCur[i] = base + excl; }
  if (i == NROW - 1) rowStart[NROW] = base + excl + c;
}

// -------- fill CSR edge lists --------
__global__ void fillKernel(const int* __restrict__ src, const int* __restrict__ tgt,
                           int* __restrict__ rowCur, int* __restrict__ list) {
  const int e = blockIdx.x * 256 + threadIdx.x;
  if (e >= E_N) return;
  const int u = src[e];
  const int p = atomicAdd(&rowCur[u], 1);
  list[p] = e;
  const int w = USER_N + tgt[e];
  const int q = atomicAdd(&rowCur[w], 1);
  list[q] = e;
}

// -------- Stage A as 8 binned GEMMs --------
__global__ void __launch_bounds__(256) stageAGemmKernel(
    const float* __restrict__ uE, const float* __restrict__ iE, const float* __restrict__ T,
    const int* __restrict__ permSrc, const int* __restrict__ permTgt,
    const int* __restrict__ perm, const int* __restrict__ cnt8,
    float* __restrict__ edge) {
  __shared__ float sT[64 * 68];
  __shared__ float sA[64 * 68];
  __shared__ int sIdxS[64], sIdxT[64];
  const int v  = blockIdx.y;
  const int nE = min(cnt8[v], BIN_CAP);
  const int t0 = blockIdx.x * 64;
  if (t0 >= nE) return;
  const int tid = threadIdx.x;
  // stage indices once
  if (tid < 64)  sIdxS[tid] = (t0 + tid < nE) ? permSrc[v * BIN_CAP + t0 + tid] : 0;
  else if (tid < 128) {
    const int l = tid - 64;
    sIdxT[l] = (t0 + l < nE) ? permTgt[v * BIN_CAP + t0 + l] : 0;
  }
  __syncthreads();
  // T[v] -> LDS (coalesced)
  #pragma unroll
  for (int r = 0; r < 4; ++r) {
    const int idx = r * 256 + tid;
    const int d = idx >> 4, kq = (idx & 15) * 4;
    *(float4*)&sT[d * 68 + kq] = *(const float4*)(T + (size_t)v * 4096 + d * 64 + kq);
  }
  // gathered uE tile -> LDS
  #pragma unroll
  for (int r = 0; r < 4; ++r) {
    const int idx = r * 256 + tid;
    const int e = idx >> 4, dq = (idx & 15) * 4;
    float4 x = make_float4(0.f, 0.f, 0.f, 0.f);
    if (t0 + e < nE) x = *(const float4*)(uE + (size_t)sIdxS[e] * 64 + dq);
    *(float4*)&sA[e * 68 + dq] = x;
  }
  __syncthreads();
  const int e0 = (tid >> 4) * 4;
  const int k0 = (tid & 15) * 4;
  float acc[4][4];
  #pragma unroll
  for (int j = 0; j < 4; ++j)
    #pragma unroll
    for (int k = 0; k < 4; ++k) acc[j][k] = 0.f;
  #pragma unroll 4
  for (int db = 0; db < 16; ++db) {
    float4 a4[4], t4[4];
    #pragma unroll
    for (int j = 0; j < 4; ++j) a4[j] = *(const float4*)&sA[(e0 + j) * 68 + db * 4];
    #pragma unroll
    for (int q = 0; q < 4; ++q) t4[q] = *(const float4*)&sT[(db * 4 + q) * 68 + k0];
    #pragma unroll
    for (int j = 0; j < 4; ++j) {
      const float aj[4] = {a4[j].x, a4[j].y, a4[j].z, a4[j].w};
      #pragma unroll
      for (int q = 0; q < 4; ++q) {
        const float a = aj[q];
        acc[j][0] += a * t4[q].x;
        acc[j][1] += a * t4[q].y;
        acc[j][2] += a * t4[q].z;
        acc[j][3] += a * t4[q].w;
      }
    }
  }
  // epilogue: * iE[tgt], scatter-store to edge[eIdx]
  #pragma unroll
  for (int j = 0; j < 4; ++j) {
    const int et = t0 + e0 + j;
    if (et < nE) {
      const int eIdx = perm[v * BIN_CAP + et];
      const int tj = sIdxT[e0 + j];
      const float4 iv = *(const float4*)(iE + (size_t)tj * 64 + k0);
      float4 r;
      r.x = acc[j][0] * iv.x; r.y = acc[j][1] * iv.y;
      r.z = acc[j][2] * iv.z; r.w = acc[j][3] * iv.w;
      *(float4*)(edge + (size_t)eIdx * 64 + k0) = r;
    }
  }
}

// -------- einsum1: C[d,h] += edge[e,d]*hyper[e,h], per-block partials --------
__global__ void __launch_bounds__(256) hyperAccumKernel(const float* __restrict__ edge,
                                                        const float* __restrict__ hyper,
                                                        float* __restrict__ partials) {
  __shared__ float sE[32 * 68];
  __shared__ float sH[32 * 132];
  const int tid = threadIdx.x;
  const int d0  = (tid & 15) * 4;
  const int h0  = (tid >> 4) * 8;
  float acc[4][8];
  #pragma unroll
  for (int j = 0; j < 4; ++j)
    #pragma unroll
    for (int i = 0; i < 8; ++i) acc[j][i] = 0.f;

  const int chunk = (E_N + NB_ACC - 1) / NB_ACC;  // 196
  const int start = blockIdx.x * chunk;
  const int end   = min(start + chunk, E_N);

  for (int base = start; base < end; base += 32) {
    __syncthreads();
    #pragma unroll
    for (int r = 0; r < 2; ++r) {
      const int idx = r * 256 + tid;
      const int e = idx >> 4, dq = (idx & 15) * 4;
      float4 v = make_float4(0.f, 0.f, 0.f, 0.f);
      if (base + e < end) v = *(const float4*)(edge + (size_t)(base + e) * 64 + dq);
      *(float4*)&sE[e * 68 + dq] = v;
    }
    #pragma unroll
    for (int r = 0; r < 4; ++r) {
      const int idx = r * 256 + tid;
      const int e = idx >> 5, hq = (idx & 31) * 4;
      float4 v = make_float4(0.f, 0.f, 0.f, 0.f);
      if (base + e < end) v = *(const float4*)(hyper + (size_t)(base + e) * 128 + hq);
      *(float4*)&sH[e * 132 + hq] = v;
    }
    __syncthreads();
    #pragma unroll 4
    for (int e = 0; e < 32; ++e) {
      const float4 ed = *(const float4*)&sE[e * 68 + d0];
      const float4 ha = *(const float4*)&sH[e * 132 + h0];
      const float4 hb = *(const float4*)&sH[e * 132 + h0 + 4];
      const float ev[4] = {ed.x, ed.y, ed.z, ed.w};
      const float hv[8] = {ha.x, ha.y, ha.z, ha.w, hb.x, hb.y, hb.z, hb.w};
      #pragma unroll
      for (int j = 0; j < 4; ++j)
        #pragma unroll
        for (int i = 0; i < 8; ++i) acc[j][i] += ev[j] * hv[i];
    }
  }
  float* pp = partials + (size_t)blockIdx.x * 8192;
  #pragma unroll
  for (int i = 0; i < 8; ++i) {
    const float4 v = make_float4(acc[0][i], acc[1][i], acc[2][i], acc[3][i]);
    *(float4*)(pp + (h0 + i) * 64 + d0) = v;
  }
}

// -------- reduce stage 1 --------
__global__ void reduce1Kernel(const float* __restrict__ partials, float* __restrict__ partial2) {
  const int i = blockIdx.x * 256 + threadIdx.x;
  const int y = blockIdx.y;
  const float* p = partials + (size_t)y * 64 * 8192 + i;
  float s0 = 0.f, s1 = 0.f, s2 = 0.f, s3 = 0.f;
  #pragma unroll 4
  for (int b = 0; b < 64; b += 4) {
    s0 += p[(size_t)(b + 0) * 8192];
    s1 += p[(size_t)(b + 1) * 8192];
    s2 += p[(size_t)(b + 2) * 8192];
    s3 += p[(size_t)(b + 3) * 8192];
  }
  partial2[y * 8192 + i] = (s0 + s1) + (s2 + s3);
}

// -------- reduce stage 2 + leaky --------
__global__ void reduce2Kernel(const float* __restrict__ partial2, float* __restrict__ HEt) {
  const int i = blockIdx.x * 256 + threadIdx.x;
  float s = 0.f;
  #pragma unroll
  for (int y = 0; y < 8; ++y) s += partial2[y * 8192 + i];
  HEt[i] = leaky(s);
}

// -------- einsum2 + residual --------
__global__ void __launch_bounds__(256) nodeUpdateKernel(const float* __restrict__ HEt,
                                                        const float* __restrict__ hyper,
                                                        float* __restrict__ edge) {
  __shared__ float sHE[8192];
  __shared__ float sHy[64 * 132];
  const int tid = threadIdx.x;
  #pragma unroll
  for (int r = 0; r < 8; ++r) {
    const int idx = r * 256 + tid;
    *(float4*)&sHE[idx * 4] = *(const float4*)(HEt + idx * 4);
  }
  const int e0 = (tid >> 4) * 4;
  const int d0 = (tid & 15) * 4;
  const int nT = (E_N + 63) >> 6;
  for (int t = blockIdx.x; t < nT; t += gridDim.x) {
    const int ge0 = t << 6;
    __syncthreads();
    #pragma unroll
    for (int r = 0; r < 8; ++r) {
      const int idx = r * 256 + tid;
      const int e = idx >> 5, hq = (idx & 31) * 4;
      float4 v = make_float4(0.f, 0.f, 0.f, 0.f);
      if (ge0 + e < E_N) v = *(const float4*)(hyper + (size_t)(ge0 + e) * 128 + hq);
      *(float4*)&sHy[e * 132 + hq] = v;
    }
    __syncthreads();
    float acc[4][4];
    #pragma unroll
    for (int j = 0; j < 4; ++j)
      #pragma unroll
      for (int k = 0; k < 4; ++k) acc[j][k] = 0.f;
    #pragma unroll 4
    for (int hb = 0; hb < 32; ++hb) {
      float4 hv4[4], he4[4];
      #pragma unroll
      for (int j = 0; j < 4; ++j) hv4[j] = *(const float4*)&sHy[(e0 + j) * 132 + hb * 4];
      #pragma unroll
      for (int q = 0; q < 4; ++q) he4[q] = *(const float4*)&sHE[(hb * 4 + q) * 64 + d0];
      #pragma unroll
      for (int j = 0; j < 4; ++j) {
        const float hj[4] = {hv4[j].x, hv4[j].y, hv4[j].z, hv4[j].w};
        #pragma unroll
        for (int q = 0; q < 4; ++q) {
          const float hq = hj[q];
          acc[j][0] += hq * he4[q].x;
          acc[j][1] += hq * he4[q].y;
          acc[j][2] += hq * he4[q].z;
          acc[j][3] += hq * he4[q].w;
        }
      }
    }
    #pragma unroll
    for (int j = 0; j < 4; ++j) {
      const int ge = ge0 + e0 + j;
      if (ge < E_N) {
        float* ep = edge + (size_t)ge * 64 + d0;
        float4 r = *(const float4*)ep;
        r.x += leaky(acc[j][0]);
        r.y += leaky(acc[j][1]);
        r.z += leaky(acc[j][2]);
        r.w += leaky(acc[j][3]);
        *(float4*)ep = r;
      }
    }
  }
}

// -------- CSR gather-sum: one wave per output row, no atomics --------
__global__ void gatherSumKernel(const float* __restrict__ edge,
                                const int* __restrict__ rowStart,
                                const int* __restrict__ list,
                                float* __restrict__ out) {
  const int lane = threadIdx.x & 63;
  const int wv = blockIdx.x * 4 + (threadIdx.x >> 6);
  const int nW = gridDim.x * 4;
  for (int r = wv; r < NROW; r += nW) {
    const int s0 = rowStart[r], s1 = rowStart[r + 1];
    float acc = 0.f;
    for (int i = s0; i < s1; ++i) {
      const int e = list[i];
      acc += edge[(size_t)e * 64 + lane];
    }
    out[(size_t)r * 64 + lane] = acc;
  }
}

extern "C" void kernel_launch(void* const* d_in, const int* in_sizes, int n_in,
                              void* d_out, int out_size, void* d_ws, size_t ws_size,
                              hipStream_t stream) {
  const float* uE    = (const float*)d_in[0];
  const float* iE    = (const float*)d_in[1];
  const float* T     = (const float*)d_in[2];
  const float* hyper = (const float*)d_in[3];
  const int*   src   = (const int*)d_in[4];
  const int*   tgt   = (const int*)d_in[5];
  const int*   val   = (const int*)d_in[6];
  float* out = (float*)d_out;
  float* ws  = (float*)d_ws;

  float* edge     = ws;                                  // 6,400,000 floats
  float* partials = ws + 6400000;                        // 512*8192 = 4,194,304 floats
  float* partial2 = ws + 6400000 + 4194304;              // 65,536
  float* HEt      = ws + 6400000 + 4194304 + 65536;      // 8,192
  // overlay on partials (dead until hyperAccum): perm + permSrc + permTgt
  int* perm    = (int*)partials;                         // 8*BIN_CAP
  int* permSrc = perm + 8 * BIN_CAP;
  int* permTgt = permSrc + 8 * BIN_CAP;
  int* cnt8    = permTgt + 8 * BIN_CAP;                  // 8 ints
  // CSR region after HEt (persists to the end)
  int* csr      = (int*)(HEt + 8192);
  int* rowStart = csr;                                   // NROW+2
  int* rowCur   = rowStart + (NROW + 2);                 // NROW+2
  int* list     = rowCur + (NROW + 2);                   // NROW
  int* cnt      = list + NROW;                           // NROW+2
  int* bsum     = cnt + (NROW + 2);                      // 1024
  int* bOff     = bsum + 1024;                           // 1024

  initCsrKernel<<<NB_SCAN + 3, 256, 0, stream>>>(cnt, cnt8);
  binKernel<<<(E_N + 255) / 256, 256, 0, stream>>>(val, src, tgt, perm, permSrc, permTgt, cnt8, cnt);
  scanSumsKernel<<<NB_SCAN, 256, 0, stream>>>(cnt, bsum);
  scanOffsKernel<<<1, 1024, 0, stream>>>(bsum, bOff);
  scanFinKernel<<<NB_SCAN, 256, 0, stream>>>(cnt, bOff, rowStart, rowCur);
  fillKernel<<<(E_N + 255) / 256, 256, 0, stream>>>(src, tgt, rowCur, list);
  stageAGemmKernel<<<dim3(BIN_CAP / 64, 8), 256, 0, stream>>>(uE, iE, T, permSrc, permTgt, perm, cnt8, edge);
  for (int layer = 0; layer < 2; ++layer) {
    hyperAccumKernel<<<NB_ACC, 256, 0, stream>>>(edge, hyper, partials);
    reduce1Kernel<<<dim3(32, 8), 256, 0, stream>>>(partials, partial2);
    reduce2Kernel<<<32, 256, 0, stream>>>(partial2, HEt);
    nodeUpdateKernel<<<512, 256, 0, stream>>>(HEt, hyper, edge);
  }
  gatherSumKernel<<<3125, 256, 0, stream>>>(edge, rowStart, list, out);
}

// Round 6
// 347.840 us; speedup vs baseline: 1.5512x; 1.0957x over previous
//
#include <hip/hip_runtime.h>

#define E_N     100000
#define USER_N  100000
#define NROW    200000
#define NB_ACC  512
#define BIN_CAP 16384
#define NB_SCAN 782     // 782*256 = 200192 >= NROW
#define E_PAD   114688  // 512 blocks * 7 chunks * 32 edges

typedef __bf16 bf16x8 __attribute__((ext_vector_type(8)));
typedef __bf16 bf16x4 __attribute__((ext_vector_type(4)));
typedef float  f32x4  __attribute__((ext_vector_type(4)));

__device__ __forceinline__ float leaky(float x) { return x > 0.f ? x : 0.5f * x; }

// -------- init: zero row counts + etype counts --------
__global__ void initCsrKernel(int* __restrict__ cnt, int* __restrict__ cnt8) {
  const int i = blockIdx.x * 256 + threadIdx.x;
  if (i < NROW + 2) cnt[i] = 0;
  if (i < 8) cnt8[i] = 0;
}

// -------- binning by etype + row histogram --------
__global__ void binKernel(const int* __restrict__ val, const int* __restrict__ src,
                          const int* __restrict__ tgt,
                          int* __restrict__ perm, int* __restrict__ permSrc,
                          int* __restrict__ permTgt,
                          int* __restrict__ cnt8, int* __restrict__ cnt) {
  __shared__ int lh[8], lbase[8];
  const int tid = threadIdx.x;
  if (tid < 8) lh[tid] = 0;
  __syncthreads();
  const int e = blockIdx.x * 256 + tid;
  int v = -1, slot = 0, s = 0, t = 0;
  if (e < E_N) {
    v = val[e]; s = src[e]; t = tgt[e];
    slot = atomicAdd(&lh[v], 1);
    atomicAdd(&cnt[s], 1);
    atomicAdd(&cnt[USER_N + t], 1);
  }
  __syncthreads();
  if (tid < 8) lbase[tid] = atomicAdd(&cnt8[tid], lh[tid]);
  __syncthreads();
  if (v >= 0) {
    const int p = v * BIN_CAP + lbase[v] + slot;
    perm[p] = e; permSrc[p] = s; permTgt[p] = t;
  }
}

// -------- scan stage 1 --------
__global__ void scanSumsKernel(const int* __restrict__ cnt, int* __restrict__ bsum) {
  __shared__ int sd[256];
  const int tid = threadIdx.x;
  const int i = blockIdx.x * 256 + tid;
  sd[tid] = (i < NROW) ? cnt[i] : 0;
  __syncthreads();
  #pragma unroll
  for (int s = 128; s > 0; s >>= 1) {
    if (tid < s) sd[tid] += sd[tid + s];
    __syncthreads();
  }
  if (tid == 0) bsum[blockIdx.x] = sd[0];
}

// -------- scan stage 2 --------
__global__ void scanOffsKernel(const int* __restrict__ bsum, int* __restrict__ bOff) {
  __shared__ int sd[1024];
  const int tid = threadIdx.x;
  const int v = (tid < NB_SCAN) ? bsum[tid] : 0;
  sd[tid] = v;
  __syncthreads();
  #pragma unroll
  for (int off = 1; off < 1024; off <<= 1) {
    const int x = (tid >= off) ? sd[tid - off] : 0;
    __syncthreads();
    sd[tid] += x;
    __syncthreads();
  }
  bOff[tid] = sd[tid] - v;
}

// -------- scan stage 3 --------
__global__ void scanFinKernel(const int* __restrict__ cnt, const int* __restrict__ bOff,
                              int* __restrict__ rowStart, int* __restrict__ rowCur) {
  __shared__ int sd[256];
  const int tid = threadIdx.x;
  const int i = blockIdx.x * 256 + tid;
  const int c = (i < NROW) ? cnt[i] : 0;
  sd[tid] = c;
  __syncthreads();
  #pragma unroll
  for (int off = 1; off < 256; off <<= 1) {
    const int x = (tid >= off) ? sd[tid - off] : 0;
    __syncthreads();
    sd[tid] += x;
    __syncthreads();
  }
  const int excl = sd[tid] - c;
  const int base = bOff[blockIdx.x];
  if (i < NROW) { rowStart[i] = base + excl; rowCur[i] = base + excl; }
  if (i == NROW - 1) rowStart[NROW] = base + excl + c;
}

// -------- fill CSR edge lists --------
__global__ void fillKernel(const int* __restrict__ src, const int* __restrict__ tgt,
                           int* __restrict__ rowCur, int* __restrict__ list) {
  const int e = blockIdx.x * 256 + threadIdx.x;
  if (e >= E_N) return;
  const int u = src[e];
  const int p = atomicAdd(&rowCur[u], 1);
  list[p] = e;
  const int w = USER_N + tgt[e];
  const int q = atomicAdd(&rowCur[w], 1);
  list[q] = e;
}

// -------- convert hyper fp32 [E,128] -> hyperT bf16 [128][E_PAD] (zero-padded) --------
__global__ void __launch_bounds__(256) convertHyperTKernel(const float* __restrict__ hyper,
                                                           __bf16* __restrict__ hyperT) {
  __shared__ __bf16 sT[128][72];
  const int tid = threadIdx.x;
  const int e0 = blockIdx.x * 64;
  const int h = tid >> 1, eoff = (tid & 1) * 32;
  if (e0 >= E_N) {
    const float4 z = make_float4(0.f, 0.f, 0.f, 0.f);
    #pragma unroll
    for (int q = 0; q < 4; ++q)
      *(float4*)((char*)(hyperT + (size_t)h * E_PAD + e0 + eoff) + q * 16) = z;
    return;
  }
  #pragma unroll
  for (int r = 0; r < 8; ++r) {
    const int idx = r * 256 + tid;
    const int e = idx >> 5, h4 = (idx & 31) * 4;
    float4 v = make_float4(0.f, 0.f, 0.f, 0.f);
    if (e0 + e < E_N) v = *(const float4*)(hyper + (size_t)(e0 + e) * 128 + h4);
    sT[h4 + 0][e] = (__bf16)v.x; sT[h4 + 1][e] = (__bf16)v.y;
    sT[h4 + 2][e] = (__bf16)v.z; sT[h4 + 3][e] = (__bf16)v.w;
  }
  __syncthreads();
  #pragma unroll
  for (int q = 0; q < 8; ++q) {
    const bf16x4 v = *(const bf16x4*)&sT[h][eoff + q * 4];
    *(bf16x4*)(hyperT + (size_t)h * E_PAD + e0 + eoff + q * 4) = v;
  }
}

// -------- convert edge fp32 [E,64] -> edgeT bf16 [64][E_PAD] (zero-padded) --------
__global__ void __launch_bounds__(256) convertEdgeTKernel(const float* __restrict__ edge,
                                                          __bf16* __restrict__ edgeT) {
  __shared__ __bf16 sT[64][72];
  const int tid = threadIdx.x;
  const int e0 = blockIdx.x * 64;
  const int d = tid >> 2, eoff = (tid & 3) * 16;
  if (e0 >= E_N) {
    const float4 z = make_float4(0.f, 0.f, 0.f, 0.f);
    #pragma unroll
    for (int q = 0; q < 2; ++q)
      *(float4*)((char*)(edgeT + (size_t)d * E_PAD + e0 + eoff) + q * 16) = z;
    return;
  }
  #pragma unroll
  for (int r = 0; r < 4; ++r) {
    const int idx = r * 256 + tid;
    const int e = idx >> 4, d4 = (idx & 15) * 4;
    float4 v = make_float4(0.f, 0.f, 0.f, 0.f);
    if (e0 + e < E_N) v = *(const float4*)(edge + (size_t)(e0 + e) * 64 + d4);
    sT[d4 + 0][e] = (__bf16)v.x; sT[d4 + 1][e] = (__bf16)v.y;
    sT[d4 + 2][e] = (__bf16)v.z; sT[d4 + 3][e] = (__bf16)v.w;
  }
  __syncthreads();
  #pragma unroll
  for (int q = 0; q < 4; ++q) {
    const bf16x4 v = *(const bf16x4*)&sT[d][eoff + q * 4];
    *(bf16x4*)(edgeT + (size_t)d * E_PAD + e0 + eoff + q * 4) = v;
  }
}

// -------- Stage A as 8 binned GEMMs (unchanged) --------
__global__ void __launch_bounds__(256) stageAGemmKernel(
    const float* __restrict__ uE, const float* __restrict__ iE, const float* __restrict__ T,
    const int* __restrict__ permSrc, const int* __restrict__ permTgt,
    const int* __restrict__ perm, const int* __restrict__ cnt8,
    float* __restrict__ edge) {
  __shared__ float sT[64 * 68];
  __shared__ float sA[64 * 68];
  __shared__ int sIdxS[64], sIdxT[64];
  const int v  = blockIdx.y;
  const int nE = min(cnt8[v], BIN_CAP);
  const int t0 = blockIdx.x * 64;
  if (t0 >= nE) return;
  const int tid = threadIdx.x;
  if (tid < 64)  sIdxS[tid] = (t0 + tid < nE) ? permSrc[v * BIN_CAP + t0 + tid] : 0;
  else if (tid < 128) {
    const int l = tid - 64;
    sIdxT[l] = (t0 + l < nE) ? permTgt[v * BIN_CAP + t0 + l] : 0;
  }
  __syncthreads();
  #pragma unroll
  for (int r = 0; r < 4; ++r) {
    const int idx = r * 256 + tid;
    const int d = idx >> 4, kq = (idx & 15) * 4;
    *(float4*)&sT[d * 68 + kq] = *(const float4*)(T + (size_t)v * 4096 + d * 64 + kq);
  }
  #pragma unroll
  for (int r = 0; r < 4; ++r) {
    const int idx = r * 256 + tid;
    const int e = idx >> 4, dq = (idx & 15) * 4;
    float4 x = make_float4(0.f, 0.f, 0.f, 0.f);
    if (t0 + e < nE) x = *(const float4*)(uE + (size_t)sIdxS[e] * 64 + dq);
    *(float4*)&sA[e * 68 + dq] = x;
  }
  __syncthreads();
  const int e0 = (tid >> 4) * 4;
  const int k0 = (tid & 15) * 4;
  float acc[4][4];
  #pragma unroll
  for (int j = 0; j < 4; ++j)
    #pragma unroll
    for (int k = 0; k < 4; ++k) acc[j][k] = 0.f;
  #pragma unroll 4
  for (int db = 0; db < 16; ++db) {
    float4 a4[4], t4[4];
    #pragma unroll
    for (int j = 0; j < 4; ++j) a4[j] = *(const float4*)&sA[(e0 + j) * 68 + db * 4];
    #pragma unroll
    for (int q = 0; q < 4; ++q) t4[q] = *(const float4*)&sT[(db * 4 + q) * 68 + k0];
    #pragma unroll
    for (int j = 0; j < 4; ++j) {
      const float aj[4] = {a4[j].x, a4[j].y, a4[j].z, a4[j].w};
      #pragma unroll
      for (int q = 0; q < 4; ++q) {
        const float a = aj[q];
        acc[j][0] += a * t4[q].x;
        acc[j][1] += a * t4[q].y;
        acc[j][2] += a * t4[q].z;
        acc[j][3] += a * t4[q].w;
      }
    }
  }
  #pragma unroll
  for (int j = 0; j < 4; ++j) {
    const int et = t0 + e0 + j;
    if (et < nE) {
      const int eIdx = perm[v * BIN_CAP + et];
      const int tj = sIdxT[e0 + j];
      const float4 iv = *(const float4*)(iE + (size_t)tj * 64 + k0);
      float4 r;
      r.x = acc[j][0] * iv.x; r.y = acc[j][1] * iv.y;
      r.z = acc[j][2] * iv.z; r.w = acc[j][3] * iv.w;
      *(float4*)(edge + (size_t)eIdx * 64 + k0) = r;
    }
  }
}

// -------- einsum1 via MFMA: partial[d*128+h] = sum_e edgeT[d][e]*hyperT[h][e] --------
// 512 blocks x 7 K-chunks of 32 edges; wave w owns h in [w*32,(w+1)*32); no LDS.
__global__ void __launch_bounds__(256) hyperAccumMfmaKernel(
    const __bf16* __restrict__ edgeT, const __bf16* __restrict__ hyperT,
    float* __restrict__ partials) {
  const int tid  = threadIdx.x;
  const int lane = tid & 63;
  const int wave = tid >> 6;
  const int l16 = lane & 15, quad = lane >> 4;
  const int base = blockIdx.x * 224;
  f32x4 acc[4][2];
  #pragma unroll
  for (int dt = 0; dt < 4; ++dt)
    #pragma unroll
    for (int ht = 0; ht < 2; ++ht) acc[dt][ht] = (f32x4){0.f, 0.f, 0.f, 0.f};
  for (int c = 0; c < 7; ++c) {
    const int e0 = base + c * 32 + quad * 8;
    bf16x8 A[4], B[2];
    #pragma unroll
    for (int dt = 0; dt < 4; ++dt)
      A[dt] = *(const bf16x8*)(edgeT + (size_t)(dt * 16 + l16) * E_PAD + e0);
    #pragma unroll
    for (int ht = 0; ht < 2; ++ht)
      B[ht] = *(const bf16x8*)(hyperT + (size_t)(wave * 32 + ht * 16 + l16) * E_PAD + e0);
    #pragma unroll
    for (int dt = 0; dt < 4; ++dt)
      #pragma unroll
      for (int ht = 0; ht < 2; ++ht)
        acc[dt][ht] = __builtin_amdgcn_mfma_f32_16x16x32_bf16(A[dt], B[ht], acc[dt][ht], 0, 0, 0);
  }
  float* pp = partials + (size_t)blockIdx.x * 8192;
  #pragma unroll
  for (int dt = 0; dt < 4; ++dt)
    #pragma unroll
    for (int ht = 0; ht < 2; ++ht) {
      const int h = wave * 32 + ht * 16 + l16;
      #pragma unroll
      for (int reg = 0; reg < 4; ++reg) {
        const int d = dt * 16 + quad * 4 + reg;
        pp[d * 128 + h] = acc[dt][ht][reg];
      }
    }
}

// -------- reduce stage 1 --------
__global__ void reduce1Kernel(const float* __restrict__ partials, float* __restrict__ partial2) {
  const int i = blockIdx.x * 256 + threadIdx.x;
  const int y = blockIdx.y;
  const float* p = partials + (size_t)y * 64 * 8192 + i;
  float s0 = 0.f, s1 = 0.f, s2 = 0.f, s3 = 0.f;
  #pragma unroll 4
  for (int b = 0; b < 64; b += 4) {
    s0 += p[(size_t)(b + 0) * 8192];
    s1 += p[(size_t)(b + 1) * 8192];
    s2 += p[(size_t)(b + 2) * 8192];
    s3 += p[(size_t)(b + 3) * 8192];
  }
  partial2[y * 8192 + i] = (s0 + s1) + (s2 + s3);
}

// -------- reduce stage 2 + leaky -> HEtT bf16 [d*128+h] --------
__global__ void reduce2Kernel(const float* __restrict__ partial2, __bf16* __restrict__ HEtT) {
  const int i = blockIdx.x * 256 + threadIdx.x;
  float s = 0.f;
  #pragma unroll
  for (int y = 0; y < 8; ++y) s += partial2[y * 8192 + i];
  HEtT[i] = (__bf16)leaky(s);
}

// -------- einsum2 via MFMA + residual; also refreshes edgeT bf16 --------
// wave handles 16-edge C tiles; B (HEtT, 16KB) hoisted into 64 VGPRs.
__global__ void __launch_bounds__(256) nodeUpdateMfmaKernel(
    const __bf16* __restrict__ HEtT, const float* __restrict__ hyper,
    float* __restrict__ edge, __bf16* __restrict__ edgeT) {
  const int tid  = threadIdx.x;
  const int lane = tid & 63;
  const int wave = tid >> 6;
  const int l16 = lane & 15, quad = lane >> 4;
  bf16x8 Bf[4][4];  // [kc][dt]
  #pragma unroll
  for (int kc = 0; kc < 4; ++kc)
    #pragma unroll
    for (int dt = 0; dt < 4; ++dt)
      Bf[kc][dt] = *(const bf16x8*)(HEtT + (dt * 16 + l16) * 128 + kc * 32 + quad * 8);
  const int wv = blockIdx.x * 4 + wave;
  for (int t = wv; t < E_N / 16; t += 2048) {
    const int e0 = t * 16;
    bf16x8 A[4];
    #pragma unroll
    for (int kc = 0; kc < 4; ++kc) {
      const float* hp = hyper + (size_t)(e0 + l16) * 128 + kc * 32 + quad * 8;
      const float4 f0 = *(const float4*)hp;
      const float4 f1 = *(const float4*)(hp + 4);
      bf16x8 a;
      a[0] = (__bf16)f0.x; a[1] = (__bf16)f0.y; a[2] = (__bf16)f0.z; a[3] = (__bf16)f0.w;
      a[4] = (__bf16)f1.x; a[5] = (__bf16)f1.y; a[6] = (__bf16)f1.z; a[7] = (__bf16)f1.w;
      A[kc] = a;
    }
    f32x4 acc[4];
    #pragma unroll
    for (int dt = 0; dt < 4; ++dt) acc[dt] = (f32x4){0.f, 0.f, 0.f, 0.f};
    #pragma unroll
    for (int kc = 0; kc < 4; ++kc)
      #pragma unroll
      for (int dt = 0; dt < 4; ++dt)
        acc[dt] = __builtin_amdgcn_mfma_f32_16x16x32_bf16(A[kc], Bf[kc][dt], acc[dt], 0, 0, 0);
    #pragma unroll
    for (int dt = 0; dt < 4; ++dt) {
      const int d = dt * 16 + l16;
      bf16x4 pk;
      #pragma unroll
      for (int reg = 0; reg < 4; ++reg) {
        const int e = e0 + quad * 4 + reg;
        float* ep = edge + (size_t)e * 64 + d;
        const float nv = *ep + leaky(acc[dt][reg]);
        *ep = nv;
        pk[reg] = (__bf16)nv;
      }
      *(bf16x4*)(edgeT + (size_t)d * E_PAD + e0 + quad * 4) = pk;
    }
  }
}

// -------- CSR gather-sum: one wave per output row, no atomics --------
__global__ void gatherSumKernel(const float* __restrict__ edge,
                                const int* __restrict__ rowStart,
                                const int* __restrict__ list,
                                float* __restrict__ out) {
  const int lane = threadIdx.x & 63;
  const int wv = blockIdx.x * 4 + (threadIdx.x >> 6);
  const int nW = gridDim.x * 4;
  for (int r = wv; r < NROW; r += nW) {
    const int s0 = rowStart[r], s1 = rowStart[r + 1];
    float acc = 0.f;
    for (int i = s0; i < s1; ++i) {
      const int e = list[i];
      acc += edge[(size_t)e * 64 + lane];
    }
    out[(size_t)r * 64 + lane] = acc;
  }
}

extern "C" void kernel_launch(void* const* d_in, const int* in_sizes, int n_in,
                              void* d_out, int out_size, void* d_ws, size_t ws_size,
                              hipStream_t stream) {
  const float* uE    = (const float*)d_in[0];
  const float* iE    = (const float*)d_in[1];
  const float* T     = (const float*)d_in[2];
  const float* hyper = (const float*)d_in[3];
  const int*   src   = (const int*)d_in[4];
  const int*   tgt   = (const int*)d_in[5];
  const int*   val   = (const int*)d_in[6];
  float* out = (float*)d_out;
  float* ws  = (float*)d_ws;

  float*  edge     = ws;                                 // 6,400,000 floats
  float*  partials = ws + 6400000;                       // 512*8192 = 4,194,304
  float*  partial2 = ws + 6400000 + 4194304;             // 65,536
  __bf16* HEtT     = (__bf16*)(ws + 6400000 + 4194304 + 65536);  // 8192 bf16 (4096 floats)
  // perm overlay on partials (dead until hyperAccum runs)
  int* perm    = (int*)partials;
  int* permSrc = perm + 8 * BIN_CAP;
  int* permTgt = permSrc + 8 * BIN_CAP;
  int* cnt8    = permTgt + 8 * BIN_CAP;
  // CSR region
  int* csr      = (int*)(ws + 6400000 + 4194304 + 65536 + 4096);
  int* rowStart = csr;                                   // NROW+2
  int* rowCur   = rowStart + (NROW + 2);                 // NROW+2
  int* list     = rowCur + (NROW + 2);                   // 2*E_N = 200,000
  int* cnt      = list + 200000;                         // NROW+2
  int* bsum     = cnt + (NROW + 2);                      // 1024
  int* bOff     = bsum + 1024;                           // 1024
  // bf16 transposed buffers (16B-aligned offsets)
  __bf16* edgeT  = (__bf16*)(ws + 11466240);             // 64  * E_PAD bf16 = 3,670,016 floats
  __bf16* hyperT = (__bf16*)(ws + 15136256);             // 128 * E_PAD bf16 = 7,340,032 floats

  initCsrKernel<<<NB_SCAN + 3, 256, 0, stream>>>(cnt, cnt8);
  binKernel<<<(E_N + 255) / 256, 256, 0, stream>>>(val, src, tgt, perm, permSrc, permTgt, cnt8, cnt);
  scanSumsKernel<<<NB_SCAN, 256, 0, stream>>>(cnt, bsum);
  scanOffsKernel<<<1, 1024, 0, stream>>>(bsum, bOff);
  scanFinKernel<<<NB_SCAN, 256, 0, stream>>>(cnt, bOff, rowStart, rowCur);
  fillKernel<<<(E_N + 255) / 256, 256, 0, stream>>>(src, tgt, rowCur, list);
  convertHyperTKernel<<<E_PAD / 64, 256, 0, stream>>>(hyper, hyperT);
  stageAGemmKernel<<<dim3(BIN_CAP / 64, 8), 256, 0, stream>>>(uE, iE, T, permSrc, permTgt, perm, cnt8, edge);
  convertEdgeTKernel<<<E_PAD / 64, 256, 0, stream>>>(edge, edgeT);
  for (int layer = 0; layer < 2; ++layer) {
    hyperAccumMfmaKernel<<<NB_ACC, 256, 0, stream>>>(edgeT, hyperT, partials);
    reduce1Kernel<<<dim3(32, 8), 256, 0, stream>>>(partials, partial2);
    reduce2Kernel<<<32, 256, 0, stream>>>(partial2, HEtT);
    nodeUpdateMfmaKernel<<<512, 256, 0, stream>>>(HEtT, hyper, edge, edgeT);
  }
  gatherSumKernel<<<3125, 256, 0, stream>>>(edge, rowStart, list, out);
}